// Round 18
// baseline (171.430 us; speedup 1.0000x reference)
//
#include <hip/hip_runtime.h>
#include <hip/hip_bf16.h>
#include <hip/hip_fp16.h>

// GCN 2-layer: z = relu(A(relu(A(xW1)+b1)W2)+b2), A = D^-1/2 (Adj+I) D^-1/2
// N=50000, E=800000, D=128. Output: float32.
// CSR via fixed-capacity bucket sort; GEMMs via MFMA 16x16x16 f16 with
// B-fragments read from pre-transposed fp16 weights in global (L1-resident)
// -> k_fused needs only the scatter's 4 KB LDS (occupancy fix for R17's 25%).

#define BK 128                      // nodes per bucket
#define CAP 4096                    // edge capacity per bucket (mean 2048 + 45 sigma)
#define PACK_ROWBITS 20             // row in bits [0,20), colLocal in [20,27)
#define NB_MAX 512
#define CHUNK 2048                  // edges per scatter block (391 blocks)

typedef __attribute__((ext_vector_type(4))) _Float16 f16x4;
typedef __attribute__((ext_vector_type(4))) float f32x4;

// ---- prep: zero gcur + transpose W1,W2 -> fp16 Wt[n][k] (replaces memset) ----
__global__ __launch_bounds__(256) void k_prep(int* gcur, int NB,
                                              const float* __restrict__ W1,
                                              const float* __restrict__ W2,
                                              _Float16* __restrict__ W1t,
                                              _Float16* __restrict__ W2t) {
    int t = blockIdx.x * 256 + threadIdx.x;
    if (t < NB) gcur[t] = 0;
    if (t < 16384) {
        int k = t >> 7, n = t & 127;
        W1t[n * 128 + k] = (_Float16)W1[t];
        W2t[n * 128 + k] = (_Float16)W2[t];
    }
}

// ---- fused: blocks [0,nScat) scatter edges; blocks [nScat,..) do layer-1 GEMM ----
// GEMM branch uses NO LDS (B-frags from global W1t) -> block LDS = 4 KB.
__global__ __launch_bounds__(256) void k_fused(const int* __restrict__ row,
                                               const int* __restrict__ col,
                                               int* gcur, unsigned* ebuf,
                                               int E, int nb,
                                               const float* __restrict__ A,
                                               const _Float16* __restrict__ W1t,
                                               __half* __restrict__ C, int M,
                                               int nScat) {
    __shared__ int h[NB_MAX];
    __shared__ int base[NB_MAX];
    const int t = threadIdx.x;

    if (blockIdx.x < nScat) {
        // ---------------- edge scatter ----------------
        const int e0 = blockIdx.x * CHUNK;
        int cs[CHUNK / 256];
        for (int i = t; i < nb; i += 256) h[i] = 0;
        __syncthreads();
#pragma unroll
        for (int q = 0; q < CHUNK / 256; q++) {
            int e = e0 + q * 256 + t;
            cs[q] = (e < E) ? col[e] : -1;
            if (cs[q] >= 0) atomicAdd(&h[cs[q] >> 7], 1);
        }
        __syncthreads();
        for (int i = t; i < nb; i += 256) {
            base[i] = h[i] ? atomicAdd(&gcur[i], h[i]) : 0;
            h[i] = 0;                               // reuse as local cursor
        }
        __syncthreads();
#pragma unroll
        for (int q = 0; q < CHUNK / 256; q++) {
            int e = e0 + q * 256 + t;
            if (cs[q] >= 0) {
                int c = cs[q];
                int b = c >> 7;
                int loc = atomicAdd(&h[b], 1);
                ebuf[b * CAP + base[b] + loc] =
                    (unsigned)row[e] | ((unsigned)(c & (BK - 1)) << PACK_ROWBITS);
            }
        }
    } else {
        // ---------------- layer-1 GEMM: C = f16(A @ W1), B from global ----------------
        const int bid = blockIdx.x - nScat;
        const int wave = t >> 6, lane = t & 63;
        const int l16 = lane & 15, g = lane >> 4;
        const int rbase = bid * 64 + wave * 16;
        int r = rbase + l16;
        if (r >= M) r = M - 1;                      // clamp (store is guarded)

        f32x4 acc[8];
#pragma unroll
        for (int ct = 0; ct < 8; ct++) acc[ct] = (f32x4){0.f, 0.f, 0.f, 0.f};

#pragma unroll
        for (int s = 0; s < 8; s++) {
            const int k0 = s * 16 + g * 4;
            float4 a4 = *(const float4*)(A + (size_t)r * 128 + k0);
            f16x4 a = (f16x4){(_Float16)a4.x, (_Float16)a4.y,
                              (_Float16)a4.z, (_Float16)a4.w};
#pragma unroll
            for (int ct = 0; ct < 8; ct++) {
                f16x4 b = *(const f16x4*)(W1t + (size_t)(ct * 16 + l16) * 128 + k0);
                acc[ct] = __builtin_amdgcn_mfma_f32_16x16x16f16(a, b, acc[ct], 0, 0, 0);
            }
        }

#pragma unroll
        for (int ct = 0; ct < 8; ct++) {
#pragma unroll
            for (int i = 0; i < 4; i++) {
                int rr = rbase + g * 4 + i;
                if (rr < M)
                    C[(size_t)rr * 128 + ct * 16 + l16] = __float2half(acc[ct][i]);
            }
        }
    }
}

// per-bucket: node degrees -> dinv/degi/startv (LDS scan) -> CSR fill.
__global__ __launch_bounds__(1024) void k_bnodefill(const unsigned* __restrict__ ebuf,
                                                    const int* __restrict__ gcur,
                                                    int* degi, float* dinv, int* startv,
                                                    int* srcs, int N) {
    __shared__ int h[BK];      // degree, then local cursor
    __shared__ int sc[BK];     // inclusive scan
    const int t = threadIdx.x, b = blockIdx.x;
    const int s = b * CAP;
    const int cnt = gcur[b];
    if (t < BK) h[t] = 0;
    __syncthreads();
    for (int i = t; i < cnt; i += 1024)
        atomicAdd(&h[(ebuf[s + i] >> PACK_ROWBITS) & (BK - 1)], 1);
    __syncthreads();
    int deg = (t < BK) ? h[t] : 0;
    if (t < BK) sc[t] = deg;
    __syncthreads();
    for (int o = 1; o < BK; o <<= 1) {
        int x = (t < BK && t >= o) ? sc[t - o] : 0;
        __syncthreads();
        if (t < BK) sc[t] += x;
        __syncthreads();
    }
    int node = b * BK + t;
    if (t < BK) {
        int lexcl = sc[t] - deg;
        if (node < N) {
            degi[node]   = deg;
            dinv[node]   = rsqrtf((float)deg + 1.0f);   // +1 self loop
            startv[node] = s + lexcl;
        }
        h[t] = lexcl;                                   // local cursor base
    }
    __syncthreads();
    for (int i = t; i < cnt; i += 1024) {
        unsigned u = ebuf[s + i];
        int c = (u >> PACK_ROWBITS) & (BK - 1);
        int loc = atomicAdd(&h[c], 1);
        srcs[s + loc] = (int)(u & ((1u << PACK_ROWBITS) - 1));
    }
}

// --- layer-2 GEMM: C[M,128] = f16(A_f16 @ W2), B from global W2t, no LDS ---
__global__ __launch_bounds__(256) void k_gemm2(const __half* __restrict__ A,
                                               const _Float16* __restrict__ W2t,
                                               __half* __restrict__ C, int M) {
    const int t = threadIdx.x;
    const int wave = t >> 6, lane = t & 63;
    const int l16 = lane & 15, g = lane >> 4;
    const int rbase = blockIdx.x * 64 + wave * 16;
    int r = rbase + l16;
    if (r >= M) r = M - 1;

    f32x4 acc[8];
#pragma unroll
    for (int ct = 0; ct < 8; ct++) acc[ct] = (f32x4){0.f, 0.f, 0.f, 0.f};

#pragma unroll
    for (int s = 0; s < 8; s++) {
        const int k0 = s * 16 + g * 4;
        f16x4 a = *(const f16x4*)((const _Float16*)A + (size_t)r * 128 + k0);
#pragma unroll
        for (int ct = 0; ct < 8; ct++) {
            f16x4 b = *(const f16x4*)(W2t + (size_t)(ct * 16 + l16) * 128 + k0);
            acc[ct] = __builtin_amdgcn_mfma_f32_16x16x16f16(a, b, acc[ct], 0, 0, 0);
        }
    }

#pragma unroll
    for (int ct = 0; ct < 8; ct++) {
#pragma unroll
        for (int i = 0; i < 4; i++) {
            int rr = rbase + g * 4 + i;
            if (rr < M)
                C[(size_t)rr * 128 + ct * 16 + l16] = __float2half(acc[ct][i]);
        }
    }
}

// --- aggregation: out = relu(di*(sum_j dj*H[j] + di*H[i]) + b), H fp16 ---
// one wave per node; padded 16-deep rounds; rows staged as raw __half2.
__global__ __launch_bounds__(256) void k_agg(const __half* __restrict__ H,
                                             const int* __restrict__ srcs,
                                             const int* __restrict__ startv,
                                             const int* __restrict__ degi,
                                             const float* __restrict__ dinv,
                                             const float* __restrict__ bias,
                                             float* __restrict__ outF,
                                             __half* __restrict__ outH, int n) {
    int wave = threadIdx.x >> 6, lane = threadIdx.x & 63;
    int node = blockIdx.x * 4 + wave;
    if (node >= n) return;
    int s0 = startv[node];
    int d = degi[node];
    float di = dinv[node];
    const __half2* Hv = (const __half2*)H;

    float2 hv = __half22float2(Hv[(size_t)node * 64 + lane]);
    float ax = di * hv.x, ay = di * hv.y;

    for (int k = 0; k < d; k += 64) {
        int take = d - k; if (take > 64) take = 64;
        int idx = (lane < take) ? srcs[s0 + k + lane] : node;
        float djl = (lane < take) ? dinv[idx] : 0.f;
        for (int u = 0; u < take; u += 16) {
            int jj[16]; __half2 hh[16];
#pragma unroll
            for (int q = 0; q < 16; q++)
                jj[q] = __shfl(idx, u + q);      // slots >= take: node, weight 0
#pragma unroll
            for (int q = 0; q < 16; q++)
                hh[q] = Hv[(size_t)jj[q] * 64 + lane];
#pragma unroll
            for (int q = 0; q < 16; q++) {
                float dj = __shfl(djl, u + q);
                float2 v = __half22float2(hh[q]);
                ax = fmaf(dj, v.x, ax);
                ay = fmaf(dj, v.y, ay);
            }
        }
    }
    float2 b2 = ((const float2*)bias)[lane];
    float ox = fmaxf(fmaf(di, ax, b2.x), 0.f);
    float oy = fmaxf(fmaf(di, ay, b2.y), 0.f);
    if (outF) {
        ((float2*)outF)[(size_t)node * 64 + lane] = make_float2(ox, oy);
    } else {
        __half2 p = __floats2half2_rn(ox, oy);
        ((__half2*)outH)[(size_t)node * 64 + lane] = p;
    }
}

extern "C" void kernel_launch(void* const* d_in, const int* in_sizes, int n_in,
                              void* d_out, int out_size, void* d_ws, size_t ws_size,
                              hipStream_t stream) {
    const float* x  = (const float*)d_in[0];
    const int*   ei = (const int*)d_in[1];
    const float* W1 = (const float*)d_in[2];
    const float* b1 = (const float*)d_in[3];
    const float* W2 = (const float*)d_in[4];
    const float* b2 = (const float*)d_in[5];
    const int N = in_sizes[0] / 128;
    const int E = in_sizes[1] / 2;
    const int NB = (N + BK - 1) / BK;       // 391 buckets

    char* w = (char*)d_ws;
    auto alloc = [&](size_t bytes) -> void* {
        void* p = (void*)w;
        w += (bytes + 255) & ~(size_t)255;
        return p;
    };
    int*      degi     = (int*)alloc((size_t)N * 4);
    float*    dinv     = (float*)alloc((size_t)N * 4);
    int*      startv   = (int*)alloc((size_t)N * 4);
    int*      gcur     = (int*)alloc((size_t)NB * 4);
    unsigned* ebuf     = (unsigned*)alloc((size_t)NB * CAP * 4);
    int*      srcs     = (int*)alloc((size_t)NB * CAP * 4);
    __half*   H        = (__half*)alloc((size_t)N * 128 * 2);
    __half*   Z        = (__half*)alloc((size_t)N * 128 * 2);
    _Float16* W1t      = (_Float16*)alloc((size_t)128 * 128 * 2);
    _Float16* W2t      = (_Float16*)alloc((size_t)128 * 128 * 2);

    const int* rowp = ei;
    const int* colp = ei + E;
    const int nScat = (E + CHUNK - 1) / CHUNK;       // 391
    const int nGemm = (N + 63) / 64;                 // 782

    k_prep<<<64, 256, 0, stream>>>(gcur, NB, W1, W2, W1t, W2t);
    k_fused<<<nScat + nGemm, 256, 0, stream>>>(rowp, colp, gcur, ebuf, E, NB,
                                               x, W1t, H, N, nScat);
    k_bnodefill<<<NB, 1024, 0, stream>>>(ebuf, gcur, degi, dinv, startv, srcs, N);

    k_agg<<<(N + 3) / 4, 256, 0, stream>>>(H, srcs, startv, degi, dinv, b1,
                                           nullptr, Z, N);
    k_gemm2<<<nGemm, 256, 0, stream>>>(Z, W2t, H, N);
    k_agg<<<(N + 3) / 4, 256, 0, stream>>>(H, srcs, startv, degi, dinv, b2,
                                           (float*)d_out, nullptr, N);
}

// Round 19
// 136.737 us; speedup vs baseline: 1.2537x; 1.2537x over previous
//
#include <hip/hip_runtime.h>
#include <hip/hip_bf16.h>
#include <hip/hip_fp16.h>

// GCN 2-layer: z = relu(A(relu(A(xW1)+b1)W2)+b2), A = D^-1/2 (Adj+I) D^-1/2
// N=50000, E=800000, D=128. Output: float32.
// CSR via fixed-capacity bucket sort; GEMMs via MFMA 16x16x16 f16 with W
// staged in LDS. k_fused GEMM blocks stage only a 64-col half of W (16.9 KB)
// so the union with the scatter stays at 8 blocks/CU (R17 was 34.8 KB -> 4).

#define BK 128                      // nodes per bucket
#define CAP 4096                    // edge capacity per bucket (mean 2048 + 45 sigma)
#define PACK_ROWBITS 20             // row in bits [0,20), colLocal in [20,27)
#define NB_MAX 512
#define CHUNK 2048                  // edges per scatter block (391 blocks)
#define WP 132                      // Wt pitch in halves: 66 mod 32 = 2 -> 4-way min

typedef __attribute__((ext_vector_type(4))) _Float16 f16x4;
typedef __attribute__((ext_vector_type(4))) float f32x4;

// ---- fused: blocks [0,nScat) scatter edges; blocks [nScat,..) layer-1 GEMM ----
// GEMM block = 64 rows x 64 cols (column-half split keeps LDS at 16.9 KB).
__global__ __launch_bounds__(256) void k_fused(const int* __restrict__ row,
                                               const int* __restrict__ col,
                                               int* gcur, unsigned* ebuf,
                                               int E, int nb,
                                               const float* __restrict__ A,
                                               const float* __restrict__ W,
                                               __half* __restrict__ C, int M,
                                               int nScat) {
    __shared__ union {
        struct { int h[NB_MAX]; int base[NB_MAX]; } sc;
        _Float16 Wt[64][WP];
    } u;
    const int t = threadIdx.x;

    if (blockIdx.x < nScat) {
        // ---------------- edge scatter ----------------
        const int e0 = blockIdx.x * CHUNK;
        int cs[CHUNK / 256];
        for (int i = t; i < nb; i += 256) u.sc.h[i] = 0;
        __syncthreads();
#pragma unroll
        for (int q = 0; q < CHUNK / 256; q++) {
            int e = e0 + q * 256 + t;
            cs[q] = (e < E) ? col[e] : -1;
            if (cs[q] >= 0) atomicAdd(&u.sc.h[cs[q] >> 7], 1);
        }
        __syncthreads();
        for (int i = t; i < nb; i += 256) {
            u.sc.base[i] = u.sc.h[i] ? atomicAdd(&gcur[i], u.sc.h[i]) : 0;
            u.sc.h[i] = 0;                          // reuse as local cursor
        }
        __syncthreads();
#pragma unroll
        for (int q = 0; q < CHUNK / 256; q++) {
            int e = e0 + q * 256 + t;
            if (cs[q] >= 0) {
                int c = cs[q];
                int b = c >> 7;
                int loc = atomicAdd(&u.sc.h[b], 1);
                ebuf[b * CAP + u.sc.base[b] + loc] =
                    (unsigned)row[e] | ((unsigned)(c & (BK - 1)) << PACK_ROWBITS);
            }
        }
    } else {
        // ------- layer-1 GEMM: C[.,colHalf*64..+63] = f16(A @ W half) -------
        const int bid = blockIdx.x - nScat;
        const int rowBlk = bid >> 1, colHalf = bid & 1;
        // stage Wt[ln][k] = W[k][colHalf*64 + ln], coalesced float4 reads
        for (int idx = t; idx < 2048; idx += 256) {
            int k = idx >> 4, nq = idx & 15;
            float4 w4 = ((const float4*)W)[k * 32 + colHalf * 16 + nq];
            int ln = nq << 2;
            u.Wt[ln + 0][k] = (_Float16)w4.x;
            u.Wt[ln + 1][k] = (_Float16)w4.y;
            u.Wt[ln + 2][k] = (_Float16)w4.z;
            u.Wt[ln + 3][k] = (_Float16)w4.w;
        }
        __syncthreads();

        const int wave = t >> 6, lane = t & 63;
        const int l16 = lane & 15, g = lane >> 4;
        const int rbase = rowBlk * 64 + wave * 16;
        int r = rbase + l16;
        if (r >= M) r = M - 1;                      // clamp (store is guarded)

        f32x4 acc[4];
#pragma unroll
        for (int ct = 0; ct < 4; ct++) acc[ct] = (f32x4){0.f, 0.f, 0.f, 0.f};

#pragma unroll
        for (int s = 0; s < 8; s++) {
            const int k0 = s * 16 + g * 4;
            float4 a4 = *(const float4*)(A + (size_t)r * 128 + k0);
            f16x4 a = (f16x4){(_Float16)a4.x, (_Float16)a4.y,
                              (_Float16)a4.z, (_Float16)a4.w};
#pragma unroll
            for (int ct = 0; ct < 4; ct++) {
                f16x4 b = *(const f16x4*)(&u.Wt[ct * 16 + l16][k0]);
                acc[ct] = __builtin_amdgcn_mfma_f32_16x16x16f16(a, b, acc[ct], 0, 0, 0);
            }
        }

#pragma unroll
        for (int ct = 0; ct < 4; ct++) {
#pragma unroll
            for (int i = 0; i < 4; i++) {
                int rr = rbase + g * 4 + i;
                if (rr < M)
                    C[(size_t)rr * 128 + colHalf * 64 + ct * 16 + l16] =
                        __float2half(acc[ct][i]);
            }
        }
    }
}

// per-bucket: node degrees -> dinv/degi/startv (LDS scan) -> CSR fill.
__global__ __launch_bounds__(1024) void k_bnodefill(const unsigned* __restrict__ ebuf,
                                                    const int* __restrict__ gcur,
                                                    int* degi, float* dinv, int* startv,
                                                    int* srcs, int N) {
    __shared__ int h[BK];      // degree, then local cursor
    __shared__ int sc[BK];     // inclusive scan
    const int t = threadIdx.x, b = blockIdx.x;
    const int s = b * CAP;
    const int cnt = gcur[b];
    if (t < BK) h[t] = 0;
    __syncthreads();
    for (int i = t; i < cnt; i += 1024)
        atomicAdd(&h[(ebuf[s + i] >> PACK_ROWBITS) & (BK - 1)], 1);
    __syncthreads();
    int deg = (t < BK) ? h[t] : 0;
    if (t < BK) sc[t] = deg;
    __syncthreads();
    for (int o = 1; o < BK; o <<= 1) {
        int x = (t < BK && t >= o) ? sc[t - o] : 0;
        __syncthreads();
        if (t < BK) sc[t] += x;
        __syncthreads();
    }
    int node = b * BK + t;
    if (t < BK) {
        int lexcl = sc[t] - deg;
        if (node < N) {
            degi[node]   = deg;
            dinv[node]   = rsqrtf((float)deg + 1.0f);   // +1 self loop
            startv[node] = s + lexcl;
        }
        h[t] = lexcl;                                   // local cursor base
    }
    __syncthreads();
    for (int i = t; i < cnt; i += 1024) {
        unsigned u = ebuf[s + i];
        int c = (u >> PACK_ROWBITS) & (BK - 1);
        int loc = atomicAdd(&h[c], 1);
        srcs[s + loc] = (int)(u & ((1u << PACK_ROWBITS) - 1));
    }
}

// --- layer-2 GEMM: C[M,128] = f16(A_f16[M,128] @ W[128,128]), LDS W, pitch 132 ---
__global__ __launch_bounds__(256) void k_gemm2(const __half* __restrict__ A,
                                               const float* __restrict__ W,
                                               __half* __restrict__ C, int M) {
    __shared__ _Float16 Wt[128][WP];
    const int t = threadIdx.x;
    for (int idx = t; idx < 4096; idx += 256) {
        int k = idx >> 5, n4 = (idx & 31) << 2;
        float4 w4 = ((const float4*)W)[idx];
        Wt[n4 + 0][k] = (_Float16)w4.x;
        Wt[n4 + 1][k] = (_Float16)w4.y;
        Wt[n4 + 2][k] = (_Float16)w4.z;
        Wt[n4 + 3][k] = (_Float16)w4.w;
    }
    __syncthreads();

    const int wave = t >> 6, lane = t & 63;
    const int l16 = lane & 15, g = lane >> 4;
    const int rbase = blockIdx.x * 64 + wave * 16;
    int r = rbase + l16;
    if (r >= M) r = M - 1;

    f32x4 acc[8];
#pragma unroll
    for (int ct = 0; ct < 8; ct++) acc[ct] = (f32x4){0.f, 0.f, 0.f, 0.f};

#pragma unroll
    for (int s = 0; s < 8; s++) {
        const int k0 = s * 16 + g * 4;
        f16x4 a = *(const f16x4*)((const _Float16*)A + (size_t)r * 128 + k0);
#pragma unroll
        for (int ct = 0; ct < 8; ct++) {
            f16x4 b = *(const f16x4*)(&Wt[ct * 16 + l16][k0]);
            acc[ct] = __builtin_amdgcn_mfma_f32_16x16x16f16(a, b, acc[ct], 0, 0, 0);
        }
    }

#pragma unroll
    for (int ct = 0; ct < 8; ct++) {
#pragma unroll
        for (int i = 0; i < 4; i++) {
            int rr = rbase + g * 4 + i;
            if (rr < M)
                C[(size_t)rr * 128 + ct * 16 + l16] = __float2half(acc[ct][i]);
        }
    }
}

// --- aggregation: out = relu(di*(sum_j dj*H[j] + di*H[i]) + b), H fp16 ---
// one wave per node; padded 16-deep rounds; rows staged as raw __half2.
__global__ __launch_bounds__(256) void k_agg(const __half* __restrict__ H,
                                             const int* __restrict__ srcs,
                                             const int* __restrict__ startv,
                                             const int* __restrict__ degi,
                                             const float* __restrict__ dinv,
                                             const float* __restrict__ bias,
                                             float* __restrict__ outF,
                                             __half* __restrict__ outH, int n) {
    int wave = threadIdx.x >> 6, lane = threadIdx.x & 63;
    int node = blockIdx.x * 4 + wave;
    if (node >= n) return;
    int s0 = startv[node];
    int d = degi[node];
    float di = dinv[node];
    const __half2* Hv = (const __half2*)H;

    float2 hv = __half22float2(Hv[(size_t)node * 64 + lane]);
    float ax = di * hv.x, ay = di * hv.y;

    for (int k = 0; k < d; k += 64) {
        int take = d - k; if (take > 64) take = 64;
        int idx = (lane < take) ? srcs[s0 + k + lane] : node;
        float djl = (lane < take) ? dinv[idx] : 0.f;
        for (int u = 0; u < take; u += 16) {
            int jj[16]; __half2 hh[16];
#pragma unroll
            for (int q = 0; q < 16; q++)
                jj[q] = __shfl(idx, u + q);      // slots >= take: node, weight 0
#pragma unroll
            for (int q = 0; q < 16; q++)
                hh[q] = Hv[(size_t)jj[q] * 64 + lane];
#pragma unroll
            for (int q = 0; q < 16; q++) {
                float dj = __shfl(djl, u + q);
                float2 v = __half22float2(hh[q]);
                ax = fmaf(dj, v.x, ax);
                ay = fmaf(dj, v.y, ay);
            }
        }
    }
    float2 b2 = ((const float2*)bias)[lane];
    float ox = fmaxf(fmaf(di, ax, b2.x), 0.f);
    float oy = fmaxf(fmaf(di, ay, b2.y), 0.f);
    if (outF) {
        ((float2*)outF)[(size_t)node * 64 + lane] = make_float2(ox, oy);
    } else {
        __half2 p = __floats2half2_rn(ox, oy);
        ((__half2*)outH)[(size_t)node * 64 + lane] = p;
    }
}

extern "C" void kernel_launch(void* const* d_in, const int* in_sizes, int n_in,
                              void* d_out, int out_size, void* d_ws, size_t ws_size,
                              hipStream_t stream) {
    const float* x  = (const float*)d_in[0];
    const int*   ei = (const int*)d_in[1];
    const float* W1 = (const float*)d_in[2];
    const float* b1 = (const float*)d_in[3];
    const float* W2 = (const float*)d_in[4];
    const float* b2 = (const float*)d_in[5];
    const int N = in_sizes[0] / 128;
    const int E = in_sizes[1] / 2;
    const int NB = (N + BK - 1) / BK;       // 391 buckets

    char* w = (char*)d_ws;
    auto alloc = [&](size_t bytes) -> void* {
        void* p = (void*)w;
        w += (bytes + 255) & ~(size_t)255;
        return p;
    };
    int*      degi     = (int*)alloc((size_t)N * 4);
    float*    dinv     = (float*)alloc((size_t)N * 4);
    int*      startv   = (int*)alloc((size_t)N * 4);
    int*      gcur     = (int*)alloc((size_t)NB * 4);
    unsigned* ebuf     = (unsigned*)alloc((size_t)NB * CAP * 4);
    int*      srcs     = (int*)alloc((size_t)NB * CAP * 4);
    __half*   H        = (__half*)alloc((size_t)N * 128 * 2);
    __half*   Z        = (__half*)alloc((size_t)N * 128 * 2);

    const int* rowp = ei;
    const int* colp = ei + E;
    const int nScat = (E + CHUNK - 1) / CHUNK;       // 391
    const int nGemm = (N + 63) / 64;                 // 782

    (void)hipMemsetAsync(gcur, 0, (size_t)NB * 4, stream);
    k_fused<<<nScat + 2 * nGemm, 256, 0, stream>>>(rowp, colp, gcur, ebuf, E, NB,
                                                   x, W1, H, N, nScat);
    k_bnodefill<<<NB, 1024, 0, stream>>>(ebuf, gcur, degi, dinv, startv, srcs, N);

    k_agg<<<(N + 3) / 4, 256, 0, stream>>>(H, srcs, startv, degi, dinv, b1,
                                           nullptr, Z, N);
    k_gemm2<<<nGemm, 256, 0, stream>>>(Z, W2, H, N);
    k_agg<<<(N + 3) / 4, 256, 0, stream>>>(H, srcs, startv, degi, dinv, b2,
                                           (float*)d_out, nullptr, N);
}

// Round 20
// 135.977 us; speedup vs baseline: 1.2607x; 1.0056x over previous
//
#include <hip/hip_runtime.h>
#include <hip/hip_bf16.h>
#include <hip/hip_fp16.h>

// GCN 2-layer: z = relu(A(relu(A(xW1)+b1)W2)+b2), A = D^-1/2 (Adj+I) D^-1/2
// N=50000, E=800000, D=128. Output: float32.
// CSR via fixed-capacity bucket sort; GEMMs via MFMA 16x16x16 f16, W staged
// in LDS (k_fused GEMM = 64-col half, 16.9 KB union). Dual sub-histograms /
// cursors in scatter + bnodefill to halve LDS-atomic serialization.

#define BK 128                      // nodes per bucket
#define CAP 4096                    // edge capacity per bucket (mean 2048 + 45 sigma)
#define PACK_ROWBITS 20             // row in bits [0,20), colLocal in [20,27)
#define NB_MAX 512
#define CHUNK 2048                  // edges per scatter block (391 blocks)
#define WP 132                      // Wt pitch in halves

typedef __attribute__((ext_vector_type(4))) _Float16 f16x4;
typedef __attribute__((ext_vector_type(4))) float f32x4;

// ---- fused: blocks [0,nScat) scatter edges; blocks [nScat,..) layer-1 GEMM ----
__global__ __launch_bounds__(256) void k_fused(const int* __restrict__ row,
                                               const int* __restrict__ col,
                                               int* gcur, unsigned* ebuf,
                                               int E, int nb,
                                               const float* __restrict__ A,
                                               const float* __restrict__ W,
                                               __half* __restrict__ C, int M,
                                               int nScat) {
    __shared__ union {
        struct { int h0[NB_MAX]; int h1[NB_MAX]; int base[NB_MAX]; int hc[NB_MAX]; } sc;
        _Float16 Wt[64][WP];
    } u;
    const int t = threadIdx.x;

    if (blockIdx.x < nScat) {
        // ---------------- edge scatter (dual sub-hist: halves t<128 / t>=128) ----
        const int e0 = blockIdx.x * CHUNK;
        const bool lo = (t < 128);
        int cs[CHUNK / 256];
        for (int i = t; i < nb; i += 256) { u.sc.h0[i] = 0; u.sc.h1[i] = 0; }
        __syncthreads();
#pragma unroll
        for (int q = 0; q < CHUNK / 256; q++) {
            int e = e0 + q * 256 + t;
            cs[q] = (e < E) ? col[e] : -1;
            if (cs[q] >= 0) atomicAdd(lo ? &u.sc.h0[cs[q] >> 7] : &u.sc.h1[cs[q] >> 7], 1);
        }
        __syncthreads();
        for (int i = t; i < nb; i += 256) {
            int tot = u.sc.h0[i] + u.sc.h1[i];
            u.sc.base[i] = tot ? atomicAdd(&gcur[i], tot) : 0;
            u.sc.hc[i] = u.sc.h0[i];                // frozen half-0 count
            u.sc.h0[i] = 0; u.sc.h1[i] = 0;         // reuse as cursors
        }
        __syncthreads();
#pragma unroll
        for (int q = 0; q < CHUNK / 256; q++) {
            int e = e0 + q * 256 + t;
            if (cs[q] >= 0) {
                int c = cs[q];
                int b = c >> 7;
                int loc = lo ? atomicAdd(&u.sc.h0[b], 1)
                             : (u.sc.hc[b] + atomicAdd(&u.sc.h1[b], 1));
                ebuf[b * CAP + u.sc.base[b] + loc] =
                    (unsigned)row[e] | ((unsigned)(c & (BK - 1)) << PACK_ROWBITS);
            }
        }
    } else {
        // ------- layer-1 GEMM: C[.,colHalf*64..+63] = f16(A @ W half) -------
        const int bid = blockIdx.x - nScat;
        const int rowBlk = bid >> 1, colHalf = bid & 1;
        for (int idx = t; idx < 2048; idx += 256) {
            int k = idx >> 4, nq = idx & 15;
            float4 w4 = ((const float4*)W)[k * 32 + colHalf * 16 + nq];
            int ln = nq << 2;
            u.Wt[ln + 0][k] = (_Float16)w4.x;
            u.Wt[ln + 1][k] = (_Float16)w4.y;
            u.Wt[ln + 2][k] = (_Float16)w4.z;
            u.Wt[ln + 3][k] = (_Float16)w4.w;
        }
        __syncthreads();

        const int wave = t >> 6, lane = t & 63;
        const int l16 = lane & 15, g = lane >> 4;
        const int rbase = rowBlk * 64 + wave * 16;
        int r = rbase + l16;
        if (r >= M) r = M - 1;                      // clamp (store is guarded)

        f32x4 acc[4];
#pragma unroll
        for (int ct = 0; ct < 4; ct++) acc[ct] = (f32x4){0.f, 0.f, 0.f, 0.f};

#pragma unroll
        for (int s = 0; s < 8; s++) {
            const int k0 = s * 16 + g * 4;
            float4 a4 = *(const float4*)(A + (size_t)r * 128 + k0);
            f16x4 a = (f16x4){(_Float16)a4.x, (_Float16)a4.y,
                              (_Float16)a4.z, (_Float16)a4.w};
#pragma unroll
            for (int ct = 0; ct < 4; ct++) {
                f16x4 b = *(const f16x4*)(&u.Wt[ct * 16 + l16][k0]);
                acc[ct] = __builtin_amdgcn_mfma_f32_16x16x16f16(a, b, acc[ct], 0, 0, 0);
            }
        }

#pragma unroll
        for (int ct = 0; ct < 4; ct++) {
#pragma unroll
            for (int i = 0; i < 4; i++) {
                int rr = rbase + g * 4 + i;
                if (rr < M)
                    C[(size_t)rr * 128 + colHalf * 64 + ct * 16 + l16] =
                        __float2half(acc[ct][i]);
            }
        }
    }
}

// per-bucket: node degrees -> dinv/degi/startv (LDS scan) -> CSR fill.
// Dual sub-histograms (halves t<512 / t>=512) to halve LDS-atomic contention.
__global__ __launch_bounds__(1024) void k_bnodefill(const unsigned* __restrict__ ebuf,
                                                    const int* __restrict__ gcur,
                                                    int* degi, float* dinv, int* startv,
                                                    int* srcs, int N) {
    __shared__ int h0[BK], h1[BK], sc[BK], lex[BK], c0[BK], c1[BK];
    const int t = threadIdx.x, b = blockIdx.x;
    const int s = b * CAP;
    const int cnt = gcur[b];
    const bool lo = (t < 512);
    if (t < BK) { h0[t] = 0; h1[t] = 0; }
    __syncthreads();
    for (int i = t; i < cnt; i += 1024) {
        int c = (ebuf[s + i] >> PACK_ROWBITS) & (BK - 1);
        atomicAdd(lo ? &h0[c] : &h1[c], 1);
    }
    __syncthreads();
    int deg = (t < BK) ? (h0[t] + h1[t]) : 0;
    if (t < BK) sc[t] = deg;
    __syncthreads();
    for (int o = 1; o < BK; o <<= 1) {
        int x = (t < BK && t >= o) ? sc[t - o] : 0;
        __syncthreads();
        if (t < BK) sc[t] += x;
        __syncthreads();
    }
    int node = b * BK + t;
    if (t < BK) {
        int lexcl = sc[t] - deg;
        if (node < N) {
            degi[node]   = deg;
            dinv[node]   = rsqrtf((float)deg + 1.0f);   // +1 self loop
            startv[node] = s + lexcl;
        }
        lex[t] = lexcl;
        c0[t] = 0; c1[t] = 0;
    }
    __syncthreads();
    for (int i = t; i < cnt; i += 1024) {
        unsigned u = ebuf[s + i];
        int c = (u >> PACK_ROWBITS) & (BK - 1);
        int loc = lo ? atomicAdd(&c0[c], 1) : (h0[c] + atomicAdd(&c1[c], 1));
        srcs[s + lex[c] + loc] = (int)(u & ((1u << PACK_ROWBITS) - 1));
    }
}

// --- layer-2 GEMM: C[M,128] = f16(A_f16[M,128] @ W[128,128]), LDS W, pitch 132 ---
__global__ __launch_bounds__(256) void k_gemm2(const __half* __restrict__ A,
                                               const float* __restrict__ W,
                                               __half* __restrict__ C, int M) {
    __shared__ _Float16 Wt[128][WP];
    const int t = threadIdx.x;
    for (int idx = t; idx < 4096; idx += 256) {
        int k = idx >> 5, n4 = (idx & 31) << 2;
        float4 w4 = ((const float4*)W)[idx];
        Wt[n4 + 0][k] = (_Float16)w4.x;
        Wt[n4 + 1][k] = (_Float16)w4.y;
        Wt[n4 + 2][k] = (_Float16)w4.z;
        Wt[n4 + 3][k] = (_Float16)w4.w;
    }
    __syncthreads();

    const int wave = t >> 6, lane = t & 63;
    const int l16 = lane & 15, g = lane >> 4;
    const int rbase = blockIdx.x * 64 + wave * 16;
    int r = rbase + l16;
    if (r >= M) r = M - 1;

    f32x4 acc[8];
#pragma unroll
    for (int ct = 0; ct < 8; ct++) acc[ct] = (f32x4){0.f, 0.f, 0.f, 0.f};

#pragma unroll
    for (int s = 0; s < 8; s++) {
        const int k0 = s * 16 + g * 4;
        f16x4 a = *(const f16x4*)((const _Float16*)A + (size_t)r * 128 + k0);
#pragma unroll
        for (int ct = 0; ct < 8; ct++) {
            f16x4 b = *(const f16x4*)(&Wt[ct * 16 + l16][k0]);
            acc[ct] = __builtin_amdgcn_mfma_f32_16x16x16f16(a, b, acc[ct], 0, 0, 0);
        }
    }

#pragma unroll
    for (int ct = 0; ct < 8; ct++) {
#pragma unroll
        for (int i = 0; i < 4; i++) {
            int rr = rbase + g * 4 + i;
            if (rr < M)
                C[(size_t)rr * 128 + ct * 16 + l16] = __float2half(acc[ct][i]);
        }
    }
}

// --- aggregation: out = relu(di*(sum_j dj*H[j] + di*H[i]) + b), H fp16 ---
__global__ __launch_bounds__(256) void k_agg(const __half* __restrict__ H,
                                             const int* __restrict__ srcs,
                                             const int* __restrict__ startv,
                                             const int* __restrict__ degi,
                                             const float* __restrict__ dinv,
                                             const float* __restrict__ bias,
                                             float* __restrict__ outF,
                                             __half* __restrict__ outH, int n) {
    int wave = threadIdx.x >> 6, lane = threadIdx.x & 63;
    int node = blockIdx.x * 4 + wave;
    if (node >= n) return;
    int s0 = startv[node];
    int d = degi[node];
    float di = dinv[node];
    const __half2* Hv = (const __half2*)H;

    float2 hv = __half22float2(Hv[(size_t)node * 64 + lane]);
    float ax = di * hv.x, ay = di * hv.y;

    for (int k = 0; k < d; k += 64) {
        int take = d - k; if (take > 64) take = 64;
        int idx = (lane < take) ? srcs[s0 + k + lane] : node;
        float djl = (lane < take) ? dinv[idx] : 0.f;
        for (int u = 0; u < take; u += 16) {
            int jj[16]; __half2 hh[16];
#pragma unroll
            for (int q = 0; q < 16; q++)
                jj[q] = __shfl(idx, u + q);      // slots >= take: node, weight 0
#pragma unroll
            for (int q = 0; q < 16; q++)
                hh[q] = Hv[(size_t)jj[q] * 64 + lane];
#pragma unroll
            for (int q = 0; q < 16; q++) {
                float dj = __shfl(djl, u + q);
                float2 v = __half22float2(hh[q]);
                ax = fmaf(dj, v.x, ax);
                ay = fmaf(dj, v.y, ay);
            }
        }
    }
    float2 b2 = ((const float2*)bias)[lane];
    float ox = fmaxf(fmaf(di, ax, b2.x), 0.f);
    float oy = fmaxf(fmaf(di, ay, b2.y), 0.f);
    if (outF) {
        ((float2*)outF)[(size_t)node * 64 + lane] = make_float2(ox, oy);
    } else {
        __half2 p = __floats2half2_rn(ox, oy);
        ((__half2*)outH)[(size_t)node * 64 + lane] = p;
    }
}

extern "C" void kernel_launch(void* const* d_in, const int* in_sizes, int n_in,
                              void* d_out, int out_size, void* d_ws, size_t ws_size,
                              hipStream_t stream) {
    const float* x  = (const float*)d_in[0];
    const int*   ei = (const int*)d_in[1];
    const float* W1 = (const float*)d_in[2];
    const float* b1 = (const float*)d_in[3];
    const float* W2 = (const float*)d_in[4];
    const float* b2 = (const float*)d_in[5];
    const int N = in_sizes[0] / 128;
    const int E = in_sizes[1] / 2;
    const int NB = (N + BK - 1) / BK;       // 391 buckets

    char* w = (char*)d_ws;
    auto alloc = [&](size_t bytes) -> void* {
        void* p = (void*)w;
        w += (bytes + 255) & ~(size_t)255;
        return p;
    };
    int*      degi     = (int*)alloc((size_t)N * 4);
    float*    dinv     = (float*)alloc((size_t)N * 4);
    int*      startv   = (int*)alloc((size_t)N * 4);
    int*      gcur     = (int*)alloc((size_t)NB * 4);
    unsigned* ebuf     = (unsigned*)alloc((size_t)NB * CAP * 4);
    int*      srcs     = (int*)alloc((size_t)NB * CAP * 4);
    __half*   H        = (__half*)alloc((size_t)N * 128 * 2);
    __half*   Z        = (__half*)alloc((size_t)N * 128 * 2);

    const int* rowp = ei;
    const int* colp = ei + E;
    const int nScat = (E + CHUNK - 1) / CHUNK;       // 391
    const int nGemm = (N + 63) / 64;                 // 782

    (void)hipMemsetAsync(gcur, 0, (size_t)NB * 4, stream);
    k_fused<<<nScat + 2 * nGemm, 256, 0, stream>>>(rowp, colp, gcur, ebuf, E, NB,
                                                   x, W1, H, N, nScat);
    k_bnodefill<<<NB, 1024, 0, stream>>>(ebuf, gcur, degi, dinv, startv, srcs, N);

    k_agg<<<(N + 3) / 4, 256, 0, stream>>>(H, srcs, startv, degi, dinv, b1,
                                           nullptr, Z, N);
    k_gemm2<<<nGemm, 256, 0, stream>>>(Z, W2, H, N);
    k_agg<<<(N + 3) / 4, 256, 0, stream>>>(H, srcs, startv, degi, dinv, b2,
                                           (float*)d_out, nullptr, N);
}